// Round 12
// baseline (106.483 us; speedup 1.0000x reference)
//
#include <hip/hip_runtime.h>
#include <hip/hip_bf16.h>
#include <math.h>

#define N 8192
#define D 64
#define INVT 20.0f
#define EPS 1e-6f
// sqrt(20/ln2): gram(Z) = 20*log2(e)*cos, so exp2(gram) = e^{20 cos}
#define ZSCALE 5.3715835f

typedef __attribute__((ext_vector_type(8))) short bf16x8;
typedef __attribute__((ext_vector_type(4))) float f32x4;

#if __has_builtin(__builtin_amdgcn_exp2f)
#define EXP2F(x) __builtin_amdgcn_exp2f(x)
#else
#define EXP2F(x) exp2f(x)
#endif

// Z layout (fragment order): G-row R, element l stored at bf16 index
//   ( (R>>4)*128 + (l>>5)*64 + ((l>>3)&3)*16 + (R&15) )*8 + (l&7)
// so the MFMA fragment load for 16-row group g, K-chunk kc is the fully
// contiguous 1 KB wave load  Zf[g*128 + kc*64 + lane].
//
// HISTORY (keep):
//  - R9: (256,5)+streamed af WITH fused logf tail -> spill (WRITE 83MB, 3.5x).
//    Tail's logf temps + extra live pointers pushed demand past the 102 cap.
//  - R10: __threadfence in all 8256 blocks -> per-XCD L2 writeback thrash,
//    loads at L3 latency, 5x slower. Device fences only in tiny kernels.
//  - R11 (=R8): 93.1 us. tiles at (256,4), af+bv resident, no tail.
//  - R12 (this): tail-free tiles at (256,5): bv resident 32 + streamed af 16
//    + acc 16 + scalars ~24 ~= 88 regs < 102 cap -> 5 waves/SIMD.

// ---------------- Kernel 1: normalize -> scaled bf16 Z (fragment order),
//                  zero part[] / lacc / cnt ----------------
__global__ __launch_bounds__(256) void prep_kernel(
    const float* __restrict__ A, const float* __restrict__ P,
    __hip_bfloat16* __restrict__ Zn, float* __restrict__ diag20,
    float* __restrict__ part, float* __restrict__ lacc, unsigned* __restrict__ cnt) {
    if (blockIdx.x < 64) part[blockIdx.x * 256 + threadIdx.x] = 0.0f;
    else if (blockIdx.x == 64 && threadIdx.x == 0) { *lacc = 0.0f; *cnt = 0u; }

    const int lane = threadIdx.x & 63;   // element index l
    const int w    = threadIdx.x >> 6;
    const int r    = blockIdx.x * 4 + w; // A/P row
    const int u    = lane >> 3, sub = lane & 7;
    const int upos = (u >> 2) * 64 + (u & 3) * 16;   // kc*64 + q*16

    float a = A[r * D + lane];
    float p = P[r * D + lane];
    float sa = a * a, sp = p * p, dp = a * p;
    #pragma unroll
    for (int off = 1; off < 64; off <<= 1) {
        sa += __shfl_xor(sa, off, 64);
        sp += __shfl_xor(sp, off, 64);
        dp += __shfl_xor(dp, off, 64);
    }
    float na  = sqrtf(sa);
    float npn = sqrtf(sp);
    {   // A-row R = r
        int g = r >> 4, l2 = r & 15;
        Zn[(g * 128 + upos + l2) * 8 + sub] = __float2bfloat16(a * (ZSCALE / na));
    }
    {   // P-row R = N + r
        int R = N + r; int g = R >> 4, l2 = R & 15;
        Zn[(g * 128 + upos + l2) * 8 + sub] = __float2bfloat16(p * (ZSCALE / npn));
    }
    if (lane == 0)
        diag20[r] = (dp / fmaxf(na * npn, EPS)) * INVT;
}

// ---------------- Kernel 2: upper-triangular tiles, (256,5) register diet ----
// 8256 blocks, one 128x128 tile each (0 <= bi <= bj < 128). Wave (wr,wc) owns
// a 64x64 subtile. bv[4][2] resident (32 VGPR); af streamed per stripe with
// one-ahead prefetch (16 VGPR); acc[4] stripe-local (16 AGPR); col partials
// as 4 scalars. No fused tail (see HISTORY R9). NO device fences (R10).
__global__ __launch_bounds__(256, 5) void tiles_kernel(
    const __hip_bfloat16* __restrict__ Zn, float* __restrict__ part) {
    __shared__ float rs[4][16][68];     // wave-local transpose; 2-way banks max
    __shared__ float merged[2][128];    // row merge over wc
    __shared__ float cmerged[2][2][64]; // col merge over wr: [wr][wc][col]

    // unrank blockIdx.x -> (bi, bj), 0 <= bi <= bj < 128
    int t = (int)blockIdx.x;
    int b = (int)((257.0f - sqrtf(66049.0f - 8.0f * (float)t)) * 0.5f);
    while (b * (257 - b) / 2 > t) --b;
    while ((b + 1) * (256 - b) / 2 <= t) ++b;
    const int bi = b;
    const int bj = b + (t - b * (257 - b) / 2);
    const bool diag = (bi == bj);

    const int tid = threadIdx.x;
    const int lane = tid & 63, w = tid >> 6;
    const int wr = w >> 1, wc = w & 1;
    const int ln = lane & 15, q = lane >> 4;
    const bf16x8* Zf = (const bf16x8*)Zn;

    // B fragments resident: contiguous 1KB wave loads
    bf16x8 bv[4][2];
    #pragma unroll
    for (int jj = 0; jj < 4; ++jj) {
        int gb = bj * 8 + wc * 4 + jj;
        #pragma unroll
        for (int kc = 0; kc < 2; ++kc)
            bv[jj][kc] = Zf[gb * 128 + kc * 64 + lane];
    }

    // A fragments streamed per stripe with one-ahead prefetch
    const int gaBase = (bi * 8 + wr * 4) * 128 + lane;
    bf16x8 afc0 = Zf[gaBase];
    bf16x8 afc1 = Zf[gaBase + 64];

    const bool dwave = diag && (wr == wc);
    const f32x4 zero = {0.0f, 0.0f, 0.0f, 0.0f};
    float csum[4] = {0.0f, 0.0f, 0.0f, 0.0f};

    #pragma unroll
    for (int ii = 0; ii < 4; ++ii) {
        bf16x8 afn0, afn1;
        if (ii < 3) {                       // prefetch next stripe's A-frags
            afn0 = Zf[gaBase + (ii + 1) * 128];
            afn1 = Zf[gaBase + (ii + 1) * 128 + 64];
        }
        // 16-row stripe: 8 MFMA into 4 accumulators (16 AGPRs live)
        f32x4 acc[4];
        #pragma unroll
        for (int jj = 0; jj < 4; ++jj)
            acc[jj] = __builtin_amdgcn_mfma_f32_16x16x32_bf16(
                afc0, bv[jj][0], zero, 0, 0, 0);
        #pragma unroll
        for (int jj = 0; jj < 4; ++jj)
            acc[jj] = __builtin_amdgcn_mfma_f32_16x16x32_bf16(
                afc1, bv[jj][1], acc[jj], 0, 0, 0);

        // immediate epilogue: exp2(gram) = e^{20 cos}; zero true-diag elems
        f32x4 rsum_ii = {};
        #pragma unroll
        for (int jj = 0; jj < 4; ++jj) {
            f32x4 e;
            #pragma unroll
            for (int r = 0; r < 4; ++r) e[r] = EXP2F(acc[jj][r]);
            if (dwave && (ii == jj)) {
                #pragma unroll
                for (int r = 0; r < 4; ++r)
                    if (ln == q * 4 + r) e[r] = 0.0f;
            }
            rsum_ii += e;
            csum[jj] += (e[0] + e[1]) + (e[2] + e[3]);
        }
        // stash this stripe's row partials straight into the transpose slot
        *(f32x4*)&rs[w][ln][ii * 16 + q * 4] = rsum_ii;
        afc0 = afn0; afc1 = afn1;
    }

    // ---- row sums: wave-local transpose read (no barrier needed) ----
    float rowsum = 0.0f;
    #pragma unroll
    for (int l = 0; l < 16; ++l) rowsum += rs[w][l][lane];  // stride-1, no conflicts
    merged[wc][wr * 64 + lane] = rowsum;

    // ---- col sums: butterfly over q, stash per (wr,wc) ----
    float cs0 = csum[0], cs1 = csum[1], cs2 = csum[2], cs3 = csum[3];
    cs0 += __shfl_xor(cs0, 16, 64); cs0 += __shfl_xor(cs0, 32, 64);
    cs1 += __shfl_xor(cs1, 16, 64); cs1 += __shfl_xor(cs1, 32, 64);
    cs2 += __shfl_xor(cs2, 16, 64); cs2 += __shfl_xor(cs2, 32, 64);
    cs3 += __shfl_xor(cs3, 16, 64); cs3 += __shfl_xor(cs3, 32, 64);
    float cval = (q == 0) ? cs0 : (q == 1) ? cs1 : (q == 2) ? cs2 : cs3;
    cmerged[wr][wc][q * 16 + ln] = cval;   // lanes (q,ln) cover all 64 cols once
    __syncthreads();

    if (tid < 128) {
        atomicAdd(part + bi * 128 + tid, merged[0][tid] + merged[1][tid]);
    } else if (!diag) {
        int col = tid - 128;               // 0..127 ; wc = col>>6
        atomicAdd(part + bj * 128 + col,
                  cmerged[0][col >> 6][col & 63] + cmerged[1][col >> 6][col & 63]);
    }
}

// ---------------- Kernel 3: per-row loss + reduce + last-block finalize ------
__global__ __launch_bounds__(256) void loss_kernel(
    const float* __restrict__ part, const float* __restrict__ diag20,
    float* __restrict__ lacc, unsigned* __restrict__ cnt, float* __restrict__ out) {
    int i = blockIdx.x * 256 + threadIdx.x;
    float v = logf(part[i] + part[N + i]) - diag20[i];
    #pragma unroll
    for (int off = 32; off > 0; off >>= 1) v += __shfl_down(v, off, 64);
    __shared__ float wsm[4];
    int lane = threadIdx.x & 63, wv = threadIdx.x >> 6;
    if (lane == 0) wsm[wv] = v;
    __syncthreads();
    if (threadIdx.x == 0) {
        atomicAdd(lacc, wsm[0] + wsm[1] + wsm[2] + wsm[3]);
        __threadfence();
        unsigned old = atomicAdd(cnt, 1u);
        if (old == (N / 256 - 1)) {
            float tot = atomicAdd(lacc, 0.0f);
            out[0] = tot * (1.0f / (float)N);
        }
    }
}

// ---------------- launch ----------------
extern "C" void kernel_launch(void* const* d_in, const int* in_sizes, int n_in,
                              void* d_out, int out_size, void* d_ws, size_t ws_size,
                              hipStream_t stream) {
    const float* A = (const float*)d_in[0];
    const float* P = (const float*)d_in[1];

    __hip_bfloat16* Zn = (__hip_bfloat16*)d_ws;                 // 2N*64 bf16 = 2 MiB
    float* diag20 = (float*)((char*)d_ws + 2u * N * D * sizeof(__hip_bfloat16));
    float* part   = diag20 + N;          // 2N floats, atomic-accumulated
    float* lacc   = part + 2 * N;
    unsigned* cnt = (unsigned*)(lacc + 1);

    prep_kernel<<<N / 4, 256, 0, stream>>>(A, P, Zn, diag20, part, lacc, cnt);

    const int nblocks = 128 * 129 / 2;   // 8256 upper-triangular 128-tiles
    tiles_kernel<<<nblocks, 256, 0, stream>>>(Zn, part);

    loss_kernel<<<N / 256, 256, 0, stream>>>(part, diag20, lacc, cnt, (float*)d_out);
}

// Round 13
// 92.503 us; speedup vs baseline: 1.1511x; 1.1511x over previous
//
#include <hip/hip_runtime.h>
#include <hip/hip_bf16.h>
#include <math.h>

#define N 8192
#define D 64
#define INVT 20.0f
#define EPS 1e-6f
// sqrt(20/ln2): gram(Z) = 20*log2(e)*cos, so exp2(gram) = e^{20 cos}
#define ZSCALE 5.3715835f

typedef __attribute__((ext_vector_type(8))) short bf16x8;
typedef __attribute__((ext_vector_type(4))) float f32x4;

#if __has_builtin(__builtin_amdgcn_exp2f)
#define EXP2F(x) __builtin_amdgcn_exp2f(x)
#else
#define EXP2F(x) exp2f(x)
#endif

// Z layout (fragment order): G-row R, element l stored at bf16 index
//   ( (R>>4)*128 + (l>>5)*64 + ((l>>3)&3)*16 + (R&15) )*8 + (l&7)
// so the MFMA fragment load for 16-row group g, K-chunk kc is the fully
// contiguous 1 KB wave load  Zf[g*128 + kc*64 + lane].
//
// HISTORY (keep):
//  - R9/R12: (256,5) cap=102 regs -> spills BOTH times (WRITE 83-85MB, 2-3x
//    slower). This kernel's live set needs ~110-120 unified regs. 4 waves/SIMD
//    [(256,4), cap 128] is the occupancy ceiling. Do not retry (256,5).
//  - R10: __threadfence in all 8256 blocks -> L2 thrash, 5x slower. Device
//    fences only in tiny kernels.
//  - R11 (=R8, best 93.1us): 1 tile/block, af+bv resident, (256,4).
//  - R13 (this): 2 consecutive ranks per block (4128 blocks); tile1 frags
//    prefetched during tile0's epilogue -> halves exposed block-startup
//    latency. Regs: tile0 compute ~105; prefetch window ~90 (af0/bv0 dead).

__device__ __forceinline__ void unrank(int t, int& bi, int& bj) {
    int b = (int)((257.0f - sqrtf(66049.0f - 8.0f * (float)t)) * 0.5f);
    while (b * (257 - b) / 2 > t) --b;
    while ((b + 1) * (256 - b) / 2 <= t) ++b;
    bi = b;
    bj = b + (t - b * (257 - b) / 2);
}

// ---------------- Kernel 1: normalize -> scaled bf16 Z (fragment order),
//                  zero part[] / lacc / cnt ----------------
__global__ __launch_bounds__(256) void prep_kernel(
    const float* __restrict__ A, const float* __restrict__ P,
    __hip_bfloat16* __restrict__ Zn, float* __restrict__ diag20,
    float* __restrict__ part, float* __restrict__ lacc, unsigned* __restrict__ cnt) {
    if (blockIdx.x < 64) part[blockIdx.x * 256 + threadIdx.x] = 0.0f;
    else if (blockIdx.x == 64 && threadIdx.x == 0) { *lacc = 0.0f; *cnt = 0u; }

    const int lane = threadIdx.x & 63;   // element index l
    const int w    = threadIdx.x >> 6;
    const int r    = blockIdx.x * 4 + w; // A/P row
    const int u    = lane >> 3, sub = lane & 7;
    const int upos = (u >> 2) * 64 + (u & 3) * 16;   // kc*64 + q*16

    float a = A[r * D + lane];
    float p = P[r * D + lane];
    float sa = a * a, sp = p * p, dp = a * p;
    #pragma unroll
    for (int off = 1; off < 64; off <<= 1) {
        sa += __shfl_xor(sa, off, 64);
        sp += __shfl_xor(sp, off, 64);
        dp += __shfl_xor(dp, off, 64);
    }
    float na  = sqrtf(sa);
    float npn = sqrtf(sp);
    {   // A-row R = r
        int g = r >> 4, l2 = r & 15;
        Zn[(g * 128 + upos + l2) * 8 + sub] = __float2bfloat16(a * (ZSCALE / na));
    }
    {   // P-row R = N + r
        int R = N + r; int g = R >> 4, l2 = R & 15;
        Zn[(g * 128 + upos + l2) * 8 + sub] = __float2bfloat16(p * (ZSCALE / npn));
    }
    if (lane == 0)
        diag20[r] = (dp / fmaxf(na * npn, EPS)) * INVT;
}

// ---------------- Kernel 2: two triangular ranks per block, prefetched ------
__global__ __launch_bounds__(256, 4) void tiles_kernel(
    const __hip_bfloat16* __restrict__ Zn, float* __restrict__ part) {
    __shared__ float rs[4][16][68];     // wave-local transpose; 2-way banks max
    __shared__ float merged[2][128];    // row merge over wc
    __shared__ float cmerged[2][2][64]; // col merge over wr: [wr][wc][col]

    const int tid = threadIdx.x;
    const int lane = tid & 63, w = tid >> 6;
    const int wr = w >> 1, wc = w & 1;
    const int ln = lane & 15, q = lane >> 4;
    const bf16x8* Zf = (const bf16x8*)Zn;

    int bi0, bj0, bi1, bj1;
    unrank(2 * (int)blockIdx.x,     bi0, bj0);
    unrank(2 * (int)blockIdx.x + 1, bi1, bj1);

    const f32x4 zero = {0.0f, 0.0f, 0.0f, 0.0f};

    // ---------------- tile 0: load fragments ----------------
    bf16x8 af0[4][2], bv0[4][2];
    #pragma unroll
    for (int ii = 0; ii < 4; ++ii) {
        int ga = bi0 * 8 + wr * 4 + ii;
        int gb = bj0 * 8 + wc * 4 + ii;
        #pragma unroll
        for (int kc = 0; kc < 2; ++kc) {
            af0[ii][kc] = Zf[ga * 128 + kc * 64 + lane];
            bv0[ii][kc] = Zf[gb * 128 + kc * 64 + lane];
        }
    }

    // ---------------- tile 0: stripes (MFMA + exp) ----------------
    const bool dwave0 = (bi0 == bj0) && (wr == wc);
    float csum[4] = {0.0f, 0.0f, 0.0f, 0.0f};
    #pragma unroll
    for (int ii = 0; ii < 4; ++ii) {
        f32x4 acc[4];
        #pragma unroll
        for (int jj = 0; jj < 4; ++jj)
            acc[jj] = __builtin_amdgcn_mfma_f32_16x16x32_bf16(
                af0[ii][0], bv0[jj][0], zero, 0, 0, 0);
        #pragma unroll
        for (int jj = 0; jj < 4; ++jj)
            acc[jj] = __builtin_amdgcn_mfma_f32_16x16x32_bf16(
                af0[ii][1], bv0[jj][1], acc[jj], 0, 0, 0);

        f32x4 rsum_ii = {};
        #pragma unroll
        for (int jj = 0; jj < 4; ++jj) {
            f32x4 e;
            #pragma unroll
            for (int r = 0; r < 4; ++r) e[r] = EXP2F(acc[jj][r]);
            if (dwave0 && (ii == jj)) {
                #pragma unroll
                for (int r = 0; r < 4; ++r)
                    if (ln == q * 4 + r) e[r] = 0.0f;
            }
            rsum_ii += e;
            csum[jj] += (e[0] + e[1]) + (e[2] + e[3]);
        }
        *(f32x4*)&rs[w][ln][ii * 16 + q * 4] = rsum_ii;
    }

    // ---------------- prefetch tile 1 fragments ----------------
    // af0/bv0 are dead past this point; tile0's remaining epilogue (LDS
    // transpose reads, butterflies, barrier, atomics ~700+ cy) covers the
    // load latency of af1/bv1.
    bf16x8 af1[4][2], bv1[4][2];
    #pragma unroll
    for (int ii = 0; ii < 4; ++ii) {
        int ga = bi1 * 8 + wr * 4 + ii;
        int gb = bj1 * 8 + wc * 4 + ii;
        #pragma unroll
        for (int kc = 0; kc < 2; ++kc) {
            af1[ii][kc] = Zf[ga * 128 + kc * 64 + lane];
            bv1[ii][kc] = Zf[gb * 128 + kc * 64 + lane];
        }
    }

    // ---------------- tile 0: reductions + atomics ----------------
    {
        float rowsum = 0.0f;
        #pragma unroll
        for (int l = 0; l < 16; ++l) rowsum += rs[w][l][lane];
        merged[wc][wr * 64 + lane] = rowsum;

        float cs0 = csum[0], cs1 = csum[1], cs2 = csum[2], cs3 = csum[3];
        cs0 += __shfl_xor(cs0, 16, 64); cs0 += __shfl_xor(cs0, 32, 64);
        cs1 += __shfl_xor(cs1, 16, 64); cs1 += __shfl_xor(cs1, 32, 64);
        cs2 += __shfl_xor(cs2, 16, 64); cs2 += __shfl_xor(cs2, 32, 64);
        cs3 += __shfl_xor(cs3, 16, 64); cs3 += __shfl_xor(cs3, 32, 64);
        float cval = (q == 0) ? cs0 : (q == 1) ? cs1 : (q == 2) ? cs2 : cs3;
        cmerged[wr][wc][q * 16 + ln] = cval;
        __syncthreads();

        if (tid < 128) {
            atomicAdd(part + bi0 * 128 + tid, merged[0][tid] + merged[1][tid]);
        } else if (bi0 != bj0) {
            int col = tid - 128;
            atomicAdd(part + bj0 * 128 + col,
                      cmerged[0][col >> 6][col & 63] + cmerged[1][col >> 6][col & 63]);
        }
    }
    __syncthreads();   // protect merged/cmerged before tile1 rewrites them

    // ---------------- tile 1: stripes (MFMA + exp) ----------------
    const bool dwave1 = (bi1 == bj1) && (wr == wc);
    float csumB[4] = {0.0f, 0.0f, 0.0f, 0.0f};
    #pragma unroll
    for (int ii = 0; ii < 4; ++ii) {
        f32x4 acc[4];
        #pragma unroll
        for (int jj = 0; jj < 4; ++jj)
            acc[jj] = __builtin_amdgcn_mfma_f32_16x16x32_bf16(
                af1[ii][0], bv1[jj][0], zero, 0, 0, 0);
        #pragma unroll
        for (int jj = 0; jj < 4; ++jj)
            acc[jj] = __builtin_amdgcn_mfma_f32_16x16x32_bf16(
                af1[ii][1], bv1[jj][1], acc[jj], 0, 0, 0);

        f32x4 rsum_ii = {};
        #pragma unroll
        for (int jj = 0; jj < 4; ++jj) {
            f32x4 e;
            #pragma unroll
            for (int r = 0; r < 4; ++r) e[r] = EXP2F(acc[jj][r]);
            if (dwave1 && (ii == jj)) {
                #pragma unroll
                for (int r = 0; r < 4; ++r)
                    if (ln == q * 4 + r) e[r] = 0.0f;
            }
            rsum_ii += e;
            csumB[jj] += (e[0] + e[1]) + (e[2] + e[3]);
        }
        *(f32x4*)&rs[w][ln][ii * 16 + q * 4] = rsum_ii;
    }

    // ---------------- tile 1: reductions + atomics ----------------
    {
        float rowsum = 0.0f;
        #pragma unroll
        for (int l = 0; l < 16; ++l) rowsum += rs[w][l][lane];
        merged[wc][wr * 64 + lane] = rowsum;

        float cs0 = csumB[0], cs1 = csumB[1], cs2 = csumB[2], cs3 = csumB[3];
        cs0 += __shfl_xor(cs0, 16, 64); cs0 += __shfl_xor(cs0, 32, 64);
        cs1 += __shfl_xor(cs1, 16, 64); cs1 += __shfl_xor(cs1, 32, 64);
        cs2 += __shfl_xor(cs2, 16, 64); cs2 += __shfl_xor(cs2, 32, 64);
        cs3 += __shfl_xor(cs3, 16, 64); cs3 += __shfl_xor(cs3, 32, 64);
        float cval = (q == 0) ? cs0 : (q == 1) ? cs1 : (q == 2) ? cs2 : cs3;
        cmerged[wr][wc][q * 16 + ln] = cval;
        __syncthreads();

        if (tid < 128) {
            atomicAdd(part + bi1 * 128 + tid, merged[0][tid] + merged[1][tid]);
        } else if (bi1 != bj1) {
            int col = tid - 128;
            atomicAdd(part + bj1 * 128 + col,
                      cmerged[0][col >> 6][col & 63] + cmerged[1][col >> 6][col & 63]);
        }
    }
}

// ---------------- Kernel 3: per-row loss + reduce + last-block finalize ------
__global__ __launch_bounds__(256) void loss_kernel(
    const float* __restrict__ part, const float* __restrict__ diag20,
    float* __restrict__ lacc, unsigned* __restrict__ cnt, float* __restrict__ out) {
    int i = blockIdx.x * 256 + threadIdx.x;
    float v = logf(part[i] + part[N + i]) - diag20[i];
    #pragma unroll
    for (int off = 32; off > 0; off >>= 1) v += __shfl_down(v, off, 64);
    __shared__ float wsm[4];
    int lane = threadIdx.x & 63, wv = threadIdx.x >> 6;
    if (lane == 0) wsm[wv] = v;
    __syncthreads();
    if (threadIdx.x == 0) {
        atomicAdd(lacc, wsm[0] + wsm[1] + wsm[2] + wsm[3]);
        __threadfence();
        unsigned old = atomicAdd(cnt, 1u);
        if (old == (N / 256 - 1)) {
            float tot = atomicAdd(lacc, 0.0f);
            out[0] = tot * (1.0f / (float)N);
        }
    }
}

// ---------------- launch ----------------
extern "C" void kernel_launch(void* const* d_in, const int* in_sizes, int n_in,
                              void* d_out, int out_size, void* d_ws, size_t ws_size,
                              hipStream_t stream) {
    const float* A = (const float*)d_in[0];
    const float* P = (const float*)d_in[1];

    __hip_bfloat16* Zn = (__hip_bfloat16*)d_ws;                 // 2N*64 bf16 = 2 MiB
    float* diag20 = (float*)((char*)d_ws + 2u * N * D * sizeof(__hip_bfloat16));
    float* part   = diag20 + N;          // 2N floats, atomic-accumulated
    float* lacc   = part + 2 * N;
    unsigned* cnt = (unsigned*)(lacc + 1);

    prep_kernel<<<N / 4, 256, 0, stream>>>(A, P, Zn, diag20, part, lacc, cnt);

    const int nblocks = 128 * 129 / 4;   // 4128 blocks, 2 triangular ranks each
    tiles_kernel<<<nblocks, 256, 0, stream>>>(Zn, part);

    loss_kernel<<<N / 256, 256, 0, stream>>>(part, diag20, lacc, cnt, (float*)d_out);
}